// Round 2
// baseline (423.009 us; speedup 1.0000x reference)
//
#include <hip/hip_runtime.h>
#include <hip/hip_bf16.h>
#include <math.h>

typedef __bf16 bf16x8 __attribute__((ext_vector_type(8)));
typedef float  f32x4  __attribute__((ext_vector_type(4)));
typedef unsigned int u32;

#define BS 4
#define CH 256
#define HW 4096
#define QB 128          // q-rows per block
#define KB 64           // j per k-tile
#define NKT (HW/KB)     // 64
#define NQT (HW/QB)     // 32

// ---------------- prep: Kn[b][j][c] bf16, Kmt'[b][c][u(j)] bf16 (mask-folded, k-permuted), norms[b][j] ----------------
__global__ __launch_bounds__(256) void prep_kernel(
    const float* __restrict__ F, const float* __restrict__ mask,
    __bf16* __restrict__ Kn, __bf16* __restrict__ Kmt, float* __restrict__ norms)
{
  __shared__ float tile[256 * 33];
  __shared__ float red[256];
  __shared__ float invs[32];
  __shared__ float mld[32];
  const int t  = threadIdx.x;
  const int b  = blockIdx.y;
  const int j0 = blockIdx.x * 32;

  {
    const int jj = t & 31, cr = t >> 5;
    for (int it = 0; it < 32; ++it) {
      int c = it * 8 + cr;
      tile[c * 33 + jj] = F[(size_t)(b * CH + c) * HW + j0 + jj];
    }
  }
  if (t < 32) mld[t] = mask[b * HW + j0 + t];
  __syncthreads();

  {
    const int jj = t & 31, part = t >> 5;
    float s = 0.f;
    for (int c = part * 32; c < part * 32 + 32; ++c) {
      float v = tile[c * 33 + jj] + 1e-7f;
      s += v * v;
    }
    red[part * 32 + jj] = s;
  }
  __syncthreads();
  if (t < 32) {
    float s = 0.f;
    for (int p = 0; p < 8; ++p) s += red[p * 32 + t];
    invs[t] = rsqrtf(s);
    norms[b * HW + j0 + t] = sqrtf(s);
  }
  __syncthreads();

  // Kn rows (coalesced over c); stash kn*mask in tile
  for (int jj = 0; jj < 32; ++jj) {
    float v  = tile[t * 33 + jj];
    float kn = (v + 1e-7f) * invs[jj];
    Kn[(size_t)(b * HW + j0 + jj) * CH + t] = (__bf16)kn;
    tile[t * 33 + jj] = kn * mld[jj];
  }
  __syncthreads();

  // Kmt' rows: col position u = 4*(jl&15) + (jl>>4) within each 64-tile
  {
    const int jj = t & 31, cr = t >> 5;
    for (int it = 0; it < 32; ++it) {
      int c = it * 8 + cr;
      int j = j0 + jj;
      int t64 = j >> 6, jl = j & 63;
      int u = ((jl & 15) << 2) | (jl >> 4);
      Kmt[(size_t)(b * CH + c) * HW + (t64 << 6) + u] = (__bf16)tile[c * 33 + jj];
    }
  }
}

// ---------------- skip flags ----------------
__global__ __launch_bounds__(256) void skip_kernel(
    const float* __restrict__ mask, float* __restrict__ flags)
{
  __shared__ float wsum[4];
  const int b = blockIdx.x, t = threadIdx.x;
  float s = 0.f;
  for (int i = t; i < HW; i += 256) s += mask[b * HW + i];
  for (int off = 32; off; off >>= 1) s += __shfl_down(s, off);
  if ((t & 63) == 0) wsum[t >> 6] = s;
  __syncthreads();
  if (t == 0) {
    float tot = wsum[0] + wsum[1] + wsum[2] + wsum[3];
    flags[b] = (tot > (float)(HW * 1 - 10)) ? 1.f : 0.f;
  }
}

__device__ inline u32 pkbf(float a, float b) {
  union { __bf16 h[2]; u32 u; } cv;
  cv.h[0] = (__bf16)a; cv.h[1] = (__bf16)b;
  return cv.u;
}

// stage one Ks tile [64 j][256 c] via global_load_lds, XOR-swizzled source (linear LDS dest)
__device__ inline void stage_ks(const __bf16* __restrict__ Kn, int b, int kt,
                                int w, int lane, char* KsB)
{
  const int l5  = lane >> 5;
  const int cb  = (lane & 31) * 16;           // col-bytes, 0..496
  #pragma unroll
  for (int i = 0; i < 8; ++i) {
    int rr = i * 8 + w * 2 + l5;              // row 0..63
    int src_cb = cb ^ ((rr & 7) << 4);
    const char* g = (const char*)(Kn + (size_t)(b * HW + kt * KB + rr) * CH) + src_cb;
    char* lds = KsB + (i * 8 + w * 2) * 512;  // wave-uniform base
    __builtin_amdgcn_global_load_lds(
        (const __attribute__((address_space(1))) u32*)g,
        (__attribute__((address_space(3))) u32*)lds, 16, 0, 0);
  }
}

// ---------------- flash attention (partial, split-j) ----------------
// block: 256 thr = 4 waves. wave w: S^T q-slab [32w,32w+32), PV c-slab [64w,64w+64).
__global__ __launch_bounds__(256, 2) void attn_kernel(
    const __bf16* __restrict__ Kn, const __bf16* __restrict__ Kmt,
    const float* __restrict__ norms,
    __bf16* __restrict__ Opart, float2* __restrict__ ml, int jn)
{
  __shared__ __align__(16) __bf16 Ks[64 * 256];
  __shared__ __align__(16) __bf16 Ps[128 * 64];
  __shared__ float alpha_s[128];
  char* KsB = (char*)Ks;
  char* PsB = (char*)Ps;

  const int t = threadIdx.x;
  const int w = t >> 6, lane = t & 63, lg = lane >> 4, lr = lane & 15;

  const int bid   = blockIdx.x;
  const int nc    = 4 * jn;
  const int qt    = bid / nc, combo = bid % nc;
  const int b     = combo / jn, js = combo % jn;
  const int KT    = NKT / jn;
  const int kt0   = js * KT;
  const int q0    = qt * QB;

  // A-frags for S^T: rows q0 + 32w + mt*16 + lr
  bf16x8 aq[2][8];
  #pragma unroll
  for (int mt = 0; mt < 2; ++mt) {
    const __bf16* qrow = Kn + (size_t)(b * HW + q0 + 32 * w + mt * 16 + lr) * CH;
    #pragma unroll
    for (int ks = 0; ks < 8; ++ks)
      aq[mt][ks] = *(const bf16x8*)(qrow + ks * 32 + lg * 8);
  }
  float nrm[2][4];
  #pragma unroll
  for (int mt = 0; mt < 2; ++mt)
    #pragma unroll
    for (int r = 0; r < 4; ++r)
      nrm[mt][r] = norms[b * HW + q0 + 32 * w + mt * 16 + lg * 4 + r];

  f32x4 acc[4][8];
  #pragma unroll
  for (int i = 0; i < 4; ++i)
    #pragma unroll
    for (int j = 0; j < 8; ++j) acc[i][j] = (f32x4)0.f;
  float m_run[2][4], l_run[2][4];
  #pragma unroll
  for (int mt = 0; mt < 2; ++mt)
    #pragma unroll
    for (int r = 0; r < 4; ++r) { m_run[mt][r] = -1e30f; l_run[mt][r] = 0.f; }

  stage_ks(Kn, b, kt0, w, lane, KsB);
  __syncthreads();

  for (int k = 0; k < KT; ++k) {
    const int kt = kt0 + k;

    // ---- S^T: 2 mt x 4 nt x 8 ks ----
    f32x4 sa[2][4];
    #pragma unroll
    for (int mt = 0; mt < 2; ++mt)
      #pragma unroll
      for (int nt = 0; nt < 4; ++nt) sa[mt][nt] = (f32x4)0.f;
    #pragma unroll
    for (int ks = 0; ks < 8; ++ks) {
      bf16x8 bb[4];
      #pragma unroll
      for (int nt = 0; nt < 4; ++nt)
        bb[nt] = *(const bf16x8*)(KsB + (nt * 16 + lr) * 512 +
                                  ((ks * 64 + lg * 16) ^ ((lr & 7) << 4)));
      #pragma unroll
      for (int mt = 0; mt < 2; ++mt)
        #pragma unroll
        for (int nt = 0; nt < 4; ++nt)
          sa[mt][nt] = __builtin_amdgcn_mfma_f32_16x16x32_bf16(aq[mt][ks], bb[nt], sa[mt][nt], 0, 0, 0);
    }

    // ---- online softmax per q-row; pack P -> Ps (u = 4*lr + nt) ----
    #pragma unroll
    for (int mt = 0; mt < 2; ++mt) {
      #pragma unroll
      for (int r = 0; r < 4; ++r) {
        float sc = nrm[mt][r];
        float s0 = sa[mt][0][r] * sc, s1 = sa[mt][1][r] * sc;
        float s2 = sa[mt][2][r] * sc, s3 = sa[mt][3][r] * sc;
        float tm = fmaxf(fmaxf(s0, s1), fmaxf(s2, s3));
        #pragma unroll
        for (int off = 8; off; off >>= 1) tm = fmaxf(tm, __shfl_xor(tm, off));
        float mn = fmaxf(m_run[mt][r], tm);
        float al = __expf(m_run[mt][r] - mn);
        m_run[mt][r] = mn;
        float e0 = __expf(s0 - mn), e1 = __expf(s1 - mn);
        float e2 = __expf(s2 - mn), e3 = __expf(s3 - mn);
        float ps = (e0 + e1) + (e2 + e3);
        #pragma unroll
        for (int off = 8; off; off >>= 1) ps += __shfl_xor(ps, off);
        l_run[mt][r] = l_run[mt][r] * al + ps;
        int q = 32 * w + mt * 16 + lg * 4 + r;
        uint2 pw; pw.x = pkbf(e0, e1); pw.y = pkbf(e2, e3);
        *(uint2*)(PsB + q * 128 + ((lr * 8) ^ ((q & 7) << 4))) = pw;
        if (lr == 0) alpha_s[q] = al;
      }
    }
    __syncthreads();

    // prefetch next Ks tile (overlaps PV)
    if (k + 1 < KT) stage_ks(Kn, b, kt + 1, w, lane, KsB);

    // ---- PV: rescale acc, then acc += Kmt' * P ----
    #pragma unroll
    for (int nt = 0; nt < 8; ++nt) {
      float al = alpha_s[nt * 16 + lr];
      #pragma unroll
      for (int mt = 0; mt < 4; ++mt) acc[mt][nt] *= al;
    }
    #pragma unroll
    for (int ks = 0; ks < 2; ++ks) {
      bf16x8 pfr[8];
      #pragma unroll
      for (int nt = 0; nt < 8; ++nt)
        pfr[nt] = *(const bf16x8*)(PsB + (nt * 16 + lr) * 128 +
                                   ((ks * 64 + lg * 16) ^ ((lr & 7) << 4)));
      #pragma unroll
      for (int mt = 0; mt < 4; ++mt) {
        bf16x8 afr = *(const bf16x8*)(Kmt + (size_t)(b * CH + 64 * w + mt * 16 + lr) * HW +
                                      (size_t)kt * KB + ks * 32 + lg * 8);
        #pragma unroll
        for (int nt = 0; nt < 8; ++nt)
          acc[mt][nt] = __builtin_amdgcn_mfma_f32_16x16x32_bf16(afr, pfr[nt], acc[mt][nt], 0, 0, 0);
      }
    }
    __syncthreads();
  }

  // ---- epilogue: store O~ (bf16) and (m,l) ----
  __bf16* op = Opart + ((size_t)(js * BS + b) * NQT + qt) * CH * QB;
  #pragma unroll
  for (int mt = 0; mt < 4; ++mt)
    #pragma unroll
    for (int nt = 0; nt < 8; ++nt)
      #pragma unroll
      for (int r = 0; r < 4; ++r) {
        int c = 64 * w + mt * 16 + lg * 4 + r;
        int q = nt * 16 + lr;
        op[(size_t)c * QB + q] = (__bf16)acc[mt][nt][r];
      }
  if (lr == 0) {
    #pragma unroll
    for (int mt = 0; mt < 2; ++mt)
      #pragma unroll
      for (int r = 0; r < 4; ++r) {
        int qg = q0 + 32 * w + mt * 16 + lg * 4 + r;
        ml[(size_t)(js * BS + b) * HW + qg] = make_float2(m_run[mt][r], l_run[mt][r]);
      }
  }
}

// ---------------- combine partials + blend ----------------
__global__ __launch_bounds__(256) void combine_kernel(
    const __bf16* __restrict__ Opart, const float2* __restrict__ ml,
    const float* __restrict__ F, const float* __restrict__ mask,
    const float* __restrict__ flags, float* __restrict__ out, int jn)
{
  const int bid = blockIdx.x;
  const int cq = bid & 3, chunk = bid >> 2;
  const int t = threadIdx.x;
  const int qg = chunk * 256 + t;          // 0..16383
  const int b  = qg >> 12, q = qg & 4095;
  const int qt = q >> 7, ql = q & 127;

  float mv[4], lv[4];
  float m = -1e30f;
  for (int js = 0; js < jn; ++js) {
    float2 e = ml[(size_t)(js * BS + b) * HW + q];
    mv[js] = e.x; lv[js] = e.y;
    m = fmaxf(m, e.x);
  }
  float L = 0.f, sc[4];
  for (int js = 0; js < jn; ++js) {
    sc[js] = __expf(mv[js] - m);
    L += lv[js] * sc[js];
  }
  float inv = 1.f / L;
  float msk = mask[b * HW + q];
  float w1 = 1.f - msk;
  bool skip = flags[b] > 0.5f;

  for (int c = cq * 64; c < cq * 64 + 64; ++c) {
    float s = 0.f;
    for (int js = 0; js < jn; ++js)
      s += (float)Opart[(((size_t)(js * BS + b) * NQT + qt) * CH + c) * QB + ql] * sc[js];
    size_t idx = ((size_t)b * CH + c) * HW + q;
    float f = F[idx];
    out[idx] = skip ? f : (s * inv * w1 + f * msk);
  }
}

extern "C" void kernel_launch(void* const* d_in, const int* in_sizes, int n_in,
                              void* d_out, int out_size, void* d_ws, size_t ws_size,
                              hipStream_t stream) {
  const float* F    = (const float*)d_in[0];
  const float* mask = (const float*)d_in[1];
  float* out = (float*)d_out;

  char* p = (char*)d_ws;
  __bf16* Kn  = (__bf16*)p;  p += (size_t)BS * HW * CH * 2;
  __bf16* Kmt = (__bf16*)p;  p += (size_t)BS * HW * CH * 2;
  float* norms = (float*)p;  p += (size_t)BS * HW * 4;
  float* flags = (float*)p;  p += 256;
  size_t used = (size_t)(p - (char*)d_ws);

  int jn = 4;
  while (jn > 1) {
    size_t need = used + (size_t)jn * ((size_t)BS * HW * 8 + (size_t)BS * NQT * CH * QB * 2);
    if (need <= ws_size) break;
    jn >>= 1;
  }
  float2* ml = (float2*)p;   p += (size_t)jn * BS * HW * 8;
  __bf16* Opart = (__bf16*)p;

  prep_kernel<<<dim3(HW / 32, BS), 256, 0, stream>>>(F, mask, Kn, Kmt, norms);
  skip_kernel<<<BS, 256, 0, stream>>>(mask, flags);
  attn_kernel<<<dim3(128 * jn), 256, 0, stream>>>(Kn, Kmt, norms, Opart, ml, jn);
  combine_kernel<<<dim3(256), 256, 0, stream>>>(Opart, ml, F, mask, flags, out, jn);
}

// Round 4
// 395.962 us; speedup vs baseline: 1.0683x; 1.0683x over previous
//
#include <hip/hip_runtime.h>
#include <hip/hip_bf16.h>
#include <math.h>

typedef __bf16 bf16x8 __attribute__((ext_vector_type(8)));
typedef float  f32x4  __attribute__((ext_vector_type(4)));
typedef unsigned int u32;

#define BS 4
#define CH 256
#define HW 4096
#define QB 128          // q-rows per block
#define KB 64           // j per k-tile
#define NKT (HW/KB)     // 64
#define NQT (HW/QB)     // 32

// ---------------- prep: Kn[b][j][c] bf16, Kmt'[b][c][u(j)] bf16 (mask-folded, k-permuted), norms[b][j] ----------------
__global__ __launch_bounds__(256) void prep_kernel(
    const float* __restrict__ F, const float* __restrict__ mask,
    __bf16* __restrict__ Kn, __bf16* __restrict__ Kmt, float* __restrict__ norms)
{
  __shared__ float tile[256 * 33];
  __shared__ float red[256];
  __shared__ float invs[32];
  __shared__ float mld[32];
  const int t  = threadIdx.x;
  const int b  = blockIdx.y;
  const int j0 = blockIdx.x * 32;

  {
    const int jj = t & 31, cr = t >> 5;
    for (int it = 0; it < 32; ++it) {
      int c = it * 8 + cr;
      tile[c * 33 + jj] = F[(size_t)(b * CH + c) * HW + j0 + jj];
    }
  }
  if (t < 32) mld[t] = mask[b * HW + j0 + t];
  __syncthreads();

  {
    const int jj = t & 31, part = t >> 5;
    float s = 0.f;
    for (int c = part * 32; c < part * 32 + 32; ++c) {
      float v = tile[c * 33 + jj] + 1e-7f;
      s += v * v;
    }
    red[part * 32 + jj] = s;
  }
  __syncthreads();
  if (t < 32) {
    float s = 0.f;
    for (int p = 0; p < 8; ++p) s += red[p * 32 + t];
    invs[t] = rsqrtf(s);
    norms[b * HW + j0 + t] = sqrtf(s);
  }
  __syncthreads();

  for (int jj = 0; jj < 32; ++jj) {
    float v  = tile[t * 33 + jj];
    float kn = (v + 1e-7f) * invs[jj];
    Kn[(size_t)(b * HW + j0 + jj) * CH + t] = (__bf16)kn;
    tile[t * 33 + jj] = kn * mld[jj];
  }
  __syncthreads();

  // Kmt' rows: col position u = 4*(jl&15) + (jl>>4) within each 64-tile
  {
    const int jj = t & 31, cr = t >> 5;
    for (int it = 0; it < 32; ++it) {
      int c = it * 8 + cr;
      int j = j0 + jj;
      int t64 = j >> 6, jl = j & 63;
      int u = ((jl & 15) << 2) | (jl >> 4);
      Kmt[(size_t)(b * CH + c) * HW + (t64 << 6) + u] = (__bf16)tile[c * 33 + jj];
    }
  }
}

// ---------------- skip flags ----------------
__global__ __launch_bounds__(256) void skip_kernel(
    const float* __restrict__ mask, float* __restrict__ flags)
{
  __shared__ float wsum[4];
  const int b = blockIdx.x, t = threadIdx.x;
  float s = 0.f;
  for (int i = t; i < HW; i += 256) s += mask[b * HW + i];
  for (int off = 32; off; off >>= 1) s += __shfl_down(s, off);
  if ((t & 63) == 0) wsum[t >> 6] = s;
  __syncthreads();
  if (t == 0) {
    float tot = wsum[0] + wsum[1] + wsum[2] + wsum[3];
    flags[b] = (tot > (float)(HW - 10)) ? 1.f : 0.f;
  }
}

__device__ inline u32 pkbf(float a, float b) {
  union { __bf16 h[2]; u32 u; } cv;
  cv.h[0] = (__bf16)a; cv.h[1] = (__bf16)b;
  return cv.u;
}

// stage one Ks tile [64 j][256 c] via global_load_lds, XOR-swizzled source (linear LDS dest)
__device__ inline void stage_ks(const __bf16* __restrict__ Kn, int b, int kt,
                                int w, int lane, char* KsB)
{
  const int l5  = lane >> 5;
  const int cb  = (lane & 31) * 16;
  #pragma unroll
  for (int i = 0; i < 8; ++i) {
    int rr = i * 8 + w * 2 + l5;
    int src_cb = cb ^ ((rr & 7) << 4);
    const char* g = (const char*)(Kn + (size_t)(b * HW + kt * KB + rr) * CH) + src_cb;
    char* lds = KsB + (i * 8 + w * 2) * 512;
    __builtin_amdgcn_global_load_lds(
        (const __attribute__((address_space(1))) u32*)g,
        (__attribute__((address_space(3))) u32*)lds, 16, 0, 0);
  }
}

// ---------------- flash attention (partial, split-j) ----------------
// block: 256 thr = 4 waves. wave w: S^T q-slab [32w,32w+32), PV c-slab [64w,64w+64).
// XCD-aware mapping: xcd owns 2 combos -> working set Kn[b] (2MB) + 2 Kmt slices (1MB) < 4MB L2.
__global__ __launch_bounds__(256, 2) void attn_kernel(
    const __bf16* __restrict__ Kn, const __bf16* __restrict__ Kmt,
    const float* __restrict__ norms,
    __bf16* __restrict__ Opart, float2* __restrict__ ml, int jn)
{
  __shared__ __align__(16) __bf16 Ks[64 * 256];
  __shared__ __align__(16) __bf16 Ps[128 * 64];
  __shared__ float alpha_s[128];
  char* KsB = (char*)Ks;
  char* PsB = (char*)Ps;

  const int t = threadIdx.x;
  const int w = t >> 6, lane = t & 63, lg = lane >> 4, lr = lane & 15;

  const int bid = blockIdx.x;
  const int nc  = 4 * jn;             // combos (b,js)
  int combo, qt;
  if (nc >= 8) {
    const int cpx  = nc >> 3;         // combos per XCD
    const int xcd  = bid & 7, slot = bid >> 3;
    combo = xcd * cpx + (slot % cpx);
    qt    = slot / cpx;
  } else {
    combo = bid % nc;
    qt    = bid / nc;
  }
  const int b   = combo / jn, js = combo % jn;
  const int KT  = NKT / jn;
  const int kt0 = js * KT;
  const int q0  = qt * QB;

  // A-frags for S^T
  bf16x8 aq[2][8];
  #pragma unroll
  for (int mt = 0; mt < 2; ++mt) {
    const __bf16* qrow = Kn + (size_t)(b * HW + q0 + 32 * w + mt * 16 + lr) * CH;
    #pragma unroll
    for (int ks = 0; ks < 8; ++ks)
      aq[mt][ks] = *(const bf16x8*)(qrow + ks * 32 + lg * 8);
  }
  float nrm[2][4];
  #pragma unroll
  for (int mt = 0; mt < 2; ++mt)
    #pragma unroll
    for (int r = 0; r < 4; ++r)
      nrm[mt][r] = norms[b * HW + q0 + 32 * w + mt * 16 + lg * 4 + r];

  f32x4 acc[4][8];
  #pragma unroll
  for (int i = 0; i < 4; ++i)
    #pragma unroll
    for (int j = 0; j < 8; ++j) acc[i][j] = (f32x4)0.f;
  float m_run[2][4], l_run[2][4];
  #pragma unroll
  for (int mt = 0; mt < 2; ++mt)
    #pragma unroll
    for (int r = 0; r < 4; ++r) { m_run[mt][r] = -1e30f; l_run[mt][r] = 0.f; }

  stage_ks(Kn, b, kt0, w, lane, KsB);
  __syncthreads();

  for (int k = 0; k < KT; ++k) {
    const int kt = kt0 + k;

    // ---- S^T ----
    f32x4 sa[2][4];
    #pragma unroll
    for (int mt = 0; mt < 2; ++mt)
      #pragma unroll
      for (int nt = 0; nt < 4; ++nt) sa[mt][nt] = (f32x4)0.f;
    #pragma unroll
    for (int ks = 0; ks < 8; ++ks) {
      bf16x8 bb[4];
      #pragma unroll
      for (int nt = 0; nt < 4; ++nt)
        bb[nt] = *(const bf16x8*)(KsB + (nt * 16 + lr) * 512 +
                                  ((ks * 64 + lg * 16) ^ ((lr & 7) << 4)));
      #pragma unroll
      for (int mt = 0; mt < 2; ++mt)
        #pragma unroll
        for (int nt = 0; nt < 4; ++nt)
          sa[mt][nt] = __builtin_amdgcn_mfma_f32_16x16x32_bf16(aq[mt][ks], bb[nt], sa[mt][nt], 0, 0, 0);
    }

    // ---- online softmax; pack P -> Ps ----
    #pragma unroll
    for (int mt = 0; mt < 2; ++mt) {
      #pragma unroll
      for (int r = 0; r < 4; ++r) {
        float sc = nrm[mt][r];
        float s0 = sa[mt][0][r] * sc, s1 = sa[mt][1][r] * sc;
        float s2 = sa[mt][2][r] * sc, s3 = sa[mt][3][r] * sc;
        float tm = fmaxf(fmaxf(s0, s1), fmaxf(s2, s3));
        #pragma unroll
        for (int off = 8; off; off >>= 1) tm = fmaxf(tm, __shfl_xor(tm, off));
        float mn = fmaxf(m_run[mt][r], tm);
        float al = __expf(m_run[mt][r] - mn);
        m_run[mt][r] = mn;
        float e0 = __expf(s0 - mn), e1 = __expf(s1 - mn);
        float e2 = __expf(s2 - mn), e3 = __expf(s3 - mn);
        float ps = (e0 + e1) + (e2 + e3);
        #pragma unroll
        for (int off = 8; off; off >>= 1) ps += __shfl_xor(ps, off);
        l_run[mt][r] = l_run[mt][r] * al + ps;
        int q = 32 * w + mt * 16 + lg * 4 + r;
        uint2 pw; pw.x = pkbf(e0, e1); pw.y = pkbf(e2, e3);
        *(uint2*)(PsB + q * 128 + ((lr * 8) ^ ((q & 7) << 4))) = pw;
        if (lr == 0) alpha_s[q] = al;
      }
    }
    __syncthreads();

    if (k + 1 < KT) stage_ks(Kn, b, kt + 1, w, lane, KsB);

    // ---- PV ----
    #pragma unroll
    for (int nt = 0; nt < 8; ++nt) {
      float al = alpha_s[nt * 16 + lr];
      #pragma unroll
      for (int mt = 0; mt < 4; ++mt) acc[mt][nt] *= al;
    }
    #pragma unroll
    for (int ks = 0; ks < 2; ++ks) {
      bf16x8 pfr[8];
      #pragma unroll
      for (int nt = 0; nt < 8; ++nt)
        pfr[nt] = *(const bf16x8*)(PsB + (nt * 16 + lr) * 128 +
                                   ((ks * 64 + lg * 16) ^ ((lr & 7) << 4)));
      #pragma unroll
      for (int mt = 0; mt < 4; ++mt) {
        bf16x8 afr = *(const bf16x8*)(Kmt + (size_t)(b * CH + 64 * w + mt * 16 + lr) * HW +
                                      (size_t)kt * KB + ks * 32 + lg * 8);
        #pragma unroll
        for (int nt = 0; nt < 8; ++nt)
          acc[mt][nt] = __builtin_amdgcn_mfma_f32_16x16x32_bf16(afr, pfr[nt], acc[mt][nt], 0, 0, 0);
      }
    }
    __syncthreads();
  }

  // ---- epilogue: store O~ as [q][c] (8B packed) and (m,l) ----
  __bf16* op = Opart + ((size_t)(js * BS + b) * NQT + qt) * QB * CH;
  #pragma unroll
  for (int mt = 0; mt < 4; ++mt) {
    const int cb = 64 * w + mt * 16 + lg * 4;
    #pragma unroll
    for (int nt = 0; nt < 8; ++nt) {
      const int q = nt * 16 + lr;
      uint2 pw;
      pw.x = pkbf(acc[mt][nt][0], acc[mt][nt][1]);
      pw.y = pkbf(acc[mt][nt][2], acc[mt][nt][3]);
      *(uint2*)(op + (size_t)q * CH + cb) = pw;
    }
  }
  if (lr == 0) {
    #pragma unroll
    for (int mt = 0; mt < 2; ++mt)
      #pragma unroll
      for (int r = 0; r < 4; ++r) {
        int qg = q0 + 32 * w + mt * 16 + lg * 4 + r;
        ml[(size_t)(js * BS + b) * HW + qg] = make_float2(m_run[mt][r], l_run[mt][r]);
      }
  }
}

// ---------------- combine partials + blend ----------------
__global__ __launch_bounds__(256) void combine_kernel(
    const __bf16* __restrict__ Opart, const float2* __restrict__ ml,
    const float* __restrict__ F, const float* __restrict__ mask,
    const float* __restrict__ flags, float* __restrict__ out, int jn)
{
  const int bid = blockIdx.x;
  const int cq = bid & 3, chunk = bid >> 2;
  const int t = threadIdx.x;
  const int qg = chunk * 256 + t;
  const int b  = qg >> 12, q = qg & 4095;
  const int qt = q >> 7, ql = q & 127;

  float mv[4], lv[4];
  float m = -1e30f;
  for (int js = 0; js < jn; ++js) {
    float2 e = ml[(size_t)(js * BS + b) * HW + q];
    mv[js] = e.x; lv[js] = e.y;
    m = fmaxf(m, e.x);
  }
  float L = 0.f, sc[4];
  for (int js = 0; js < jn; ++js) {
    sc[js] = __expf(mv[js] - m);
    L += lv[js] * sc[js];
  }
  float inv = 1.f / L;
  float msk = mask[b * HW + q];
  float w1 = 1.f - msk;
  bool skip = flags[b] > 0.5f;

  const __bf16* opq[4];
  for (int js = 0; js < jn; ++js)
    opq[js] = Opart + (((size_t)(js * BS + b) * NQT + qt) * QB + ql) * CH;

  for (int c0 = cq * 64; c0 < cq * 64 + 64; c0 += 8) {
    float s8[8];
    #pragma unroll
    for (int e = 0; e < 8; ++e) s8[e] = 0.f;
    for (int js = 0; js < jn; ++js) {
      bf16x8 v = *(const bf16x8*)(opq[js] + c0);
      #pragma unroll
      for (int e = 0; e < 8; ++e) s8[e] += (float)v[e] * sc[js];
    }
    #pragma unroll
    for (int e = 0; e < 8; ++e) {
      size_t idx = ((size_t)b * CH + c0 + e) * HW + q;
      float f = F[idx];
      out[idx] = skip ? f : (s8[e] * inv * w1 + f * msk);
    }
  }
}

extern "C" void kernel_launch(void* const* d_in, const int* in_sizes, int n_in,
                              void* d_out, int out_size, void* d_ws, size_t ws_size,
                              hipStream_t stream) {
  const float* F    = (const float*)d_in[0];
  const float* mask = (const float*)d_in[1];
  float* out = (float*)d_out;

  char* p = (char*)d_ws;
  __bf16* Kn  = (__bf16*)p;  p += (size_t)BS * HW * CH * 2;
  __bf16* Kmt = (__bf16*)p;  p += (size_t)BS * HW * CH * 2;
  float* norms = (float*)p;  p += (size_t)BS * HW * 4;
  float* flags = (float*)p;  p += 256;
  size_t used = (size_t)(p - (char*)d_ws);

  int jn = 4;
  while (jn > 1) {
    size_t need = used + (size_t)jn * ((size_t)BS * HW * 8 + (size_t)BS * NQT * CH * QB * 2);
    if (need <= ws_size) break;
    jn >>= 1;
  }
  float2* ml = (float2*)p;   p += (size_t)jn * BS * HW * 8;
  __bf16* Opart = (__bf16*)p;

  prep_kernel<<<dim3(HW / 32, BS), 256, 0, stream>>>(F, mask, Kn, Kmt, norms);
  skip_kernel<<<BS, 256, 0, stream>>>(mask, flags);
  attn_kernel<<<dim3(NQT * 4 * jn), 256, 0, stream>>>(Kn, Kmt, norms, Opart, ml, jn);
  combine_kernel<<<dim3(256), 256, 0, stream>>>(Opart, ml, F, mask, flags, out, jn);
}

// Round 5
// 259.230 us; speedup vs baseline: 1.6318x; 1.5275x over previous
//
#include <hip/hip_runtime.h>
#include <hip/hip_bf16.h>
#include <math.h>

typedef __bf16 bf16x8 __attribute__((ext_vector_type(8)));
typedef float  f32x4  __attribute__((ext_vector_type(4)));
typedef unsigned int u32;

#define BS 4
#define CH 256
#define HW 4096
#define QB 64           // q-rows per block
#define KB 64           // j per k-tile
#define NKT (HW/KB)     // 64
#define NQT (HW/QB)     // 64

// ---------------- prep: Kn[b][j][c] bf16, Kmt'[b][c][u(j)] bf16 (mask-folded, k-permuted), norms[b][j] ----------------
__global__ __launch_bounds__(256) void prep_kernel(
    const float* __restrict__ F, const float* __restrict__ mask,
    __bf16* __restrict__ Kn, __bf16* __restrict__ Kmt, float* __restrict__ norms)
{
  __shared__ float tile[256 * 33];
  __shared__ float red[256];
  __shared__ float invs[32];
  __shared__ float mld[32];
  const int t  = threadIdx.x;
  const int b  = blockIdx.y;
  const int j0 = blockIdx.x * 32;

  {
    const int jj = t & 31, cr = t >> 5;
    for (int it = 0; it < 32; ++it) {
      int c = it * 8 + cr;
      tile[c * 33 + jj] = F[(size_t)(b * CH + c) * HW + j0 + jj];
    }
  }
  if (t < 32) mld[t] = mask[b * HW + j0 + t];
  __syncthreads();

  {
    const int jj = t & 31, part = t >> 5;
    float s = 0.f;
    for (int c = part * 32; c < part * 32 + 32; ++c) {
      float v = tile[c * 33 + jj] + 1e-7f;
      s += v * v;
    }
    red[part * 32 + jj] = s;
  }
  __syncthreads();
  if (t < 32) {
    float s = 0.f;
    for (int p = 0; p < 8; ++p) s += red[p * 32 + t];
    invs[t] = rsqrtf(s);
    norms[b * HW + j0 + t] = sqrtf(s);
  }
  __syncthreads();

  for (int jj = 0; jj < 32; ++jj) {
    float v  = tile[t * 33 + jj];
    float kn = (v + 1e-7f) * invs[jj];
    Kn[(size_t)(b * HW + j0 + jj) * CH + t] = (__bf16)kn;
    tile[t * 33 + jj] = kn * mld[jj];
  }
  __syncthreads();

  // Kmt' rows: col position u = 4*(jl&15) + (jl>>4) within each 64-tile
  {
    const int jj = t & 31, cr = t >> 5;
    for (int it = 0; it < 32; ++it) {
      int c = it * 8 + cr;
      int j = j0 + jj;
      int t64 = j >> 6, jl = j & 63;
      int u = ((jl & 15) << 2) | (jl >> 4);
      Kmt[(size_t)(b * CH + c) * HW + (t64 << 6) + u] = (__bf16)tile[c * 33 + jj];
    }
  }
}

// ---------------- skip flags ----------------
__global__ __launch_bounds__(256) void skip_kernel(
    const float* __restrict__ mask, float* __restrict__ flags)
{
  __shared__ float wsum[4];
  const int b = blockIdx.x, t = threadIdx.x;
  float s = 0.f;
  for (int i = t; i < HW; i += 256) s += mask[b * HW + i];
  for (int off = 32; off; off >>= 1) s += __shfl_down(s, off);
  if ((t & 63) == 0) wsum[t >> 6] = s;
  __syncthreads();
  if (t == 0) {
    float tot = wsum[0] + wsum[1] + wsum[2] + wsum[3];
    flags[b] = (tot > (float)(HW - 10)) ? 1.f : 0.f;
  }
}

__device__ inline u32 pkbf(float a, float b) {
  union { __bf16 h[2]; u32 u; } cv;
  cv.h[0] = (__bf16)a; cv.h[1] = (__bf16)b;
  return cv.u;
}

// ---------------- flash attention (partial, split-j, register-staged LDS) ----------------
// block: 256 thr = 4 waves. wave w: S^T q-slab [16w,16w+16), PV c-slab [64w,64w+64).
// grid 512: combo = bid&7 (one (b,js) per XCD under %8 round-robin), qt = bid>>3.
__global__ __launch_bounds__(256, 2) void attn_kernel(
    const __bf16* __restrict__ Kn, const __bf16* __restrict__ Kmt,
    const float* __restrict__ norms,
    __bf16* __restrict__ Opart, float2* __restrict__ ml, int jn)
{
  __shared__ __align__(16) __bf16 Ks[64 * 256];  // 32 KB, rows 512B, XOR-swizzled
  __shared__ __align__(16) __bf16 Ps[64 * 64];   // 8 KB, rows 128B, XOR-swizzled
  __shared__ float alpha_s[64];
  char* KsB = (char*)Ks;
  char* PsB = (char*)Ps;

  const int t = threadIdx.x;
  const int w = t >> 6, lane = t & 63, lg = lane >> 4, lr = lane & 15;

  const int bid = blockIdx.x;
  const int nc  = 4 * jn;             // combos (b,js)
  int combo, qt;
  if (nc == 8) { combo = bid & 7; qt = bid >> 3; }
  else         { combo = bid % nc; qt = bid / nc; }
  const int b   = combo / jn, js = combo % jn;
  const int KT  = NKT / jn;
  const int kt0 = js * KT;
  const int q0  = qt * QB;

  // staging geometry: thread t covers rows r0+8i, bytes cb..cb+15
  const int r0 = t >> 5;              // 0..7
  const int cb = (t & 31) * 16;       // 0..496
  const int swzk = (r0 & 7) << 4;     // write-side XOR key (rows r0+8i share r&7)

  // A-frags for S^T: rows q0 + 16w + lr
  bf16x8 aq[8];
  {
    const __bf16* qrow = Kn + (size_t)(b * HW + q0 + 16 * w + lr) * CH;
    #pragma unroll
    for (int ks = 0; ks < 8; ++ks)
      aq[ks] = *(const bf16x8*)(qrow + ks * 32 + lg * 8);
  }
  float nrm[4];
  #pragma unroll
  for (int r = 0; r < 4; ++r)
    nrm[r] = norms[b * HW + q0 + 16 * w + lg * 4 + r];

  f32x4 acc[4][4];
  #pragma unroll
  for (int i = 0; i < 4; ++i)
    #pragma unroll
    for (int j = 0; j < 4; ++j) acc[i][j] = (f32x4)0.f;
  float m_run[4], l_run[4];
  #pragma unroll
  for (int r = 0; r < 4; ++r) { m_run[r] = -1e30f; l_run[r] = 0.f; }

  // prologue: stage tile kt0 (regular loads -> swizzled ds_write)
  {
    uint4 st[8];
    #pragma unroll
    for (int i = 0; i < 8; ++i)
      st[i] = *(const uint4*)((const char*)(Kn + (size_t)(b * HW + kt0 * KB + r0 + 8 * i) * CH) + cb);
    #pragma unroll
    for (int i = 0; i < 8; ++i)
      *(uint4*)(KsB + (r0 + 8 * i) * 512 + (cb ^ swzk)) = st[i];
  }
  __syncthreads();

  for (int k = 0; k < KT; ++k) {
    const int kt = kt0 + k;

    // prefetch this tile's Kmt A-frags (consumed in PV)
    bf16x8 km[2][4];
    #pragma unroll
    for (int ks = 0; ks < 2; ++ks)
      #pragma unroll
      for (int mt = 0; mt < 4; ++mt)
        km[ks][mt] = *(const bf16x8*)(Kmt + (size_t)(b * CH + 64 * w + mt * 16 + lr) * HW +
                                      (size_t)kt * KB + ks * 32 + lg * 8);

    // issue next tile's staging loads (latency hides under S^T + softmax)
    uint4 st[8];
    if (k + 1 < KT) {
      #pragma unroll
      for (int i = 0; i < 8; ++i)
        st[i] = *(const uint4*)((const char*)(Kn + (size_t)(b * HW + (kt + 1) * KB + r0 + 8 * i) * CH) + cb);
    }

    // ---- S^T: 4 nt x 8 ks ----
    f32x4 sa[4];
    #pragma unroll
    for (int nt = 0; nt < 4; ++nt) sa[nt] = (f32x4)0.f;
    #pragma unroll
    for (int ks = 0; ks < 8; ++ks) {
      bf16x8 bb[4];
      #pragma unroll
      for (int nt = 0; nt < 4; ++nt)
        bb[nt] = *(const bf16x8*)(KsB + (nt * 16 + lr) * 512 +
                                  ((ks * 64 + lg * 16) ^ ((lr & 7) << 4)));
      #pragma unroll
      for (int nt = 0; nt < 4; ++nt)
        sa[nt] = __builtin_amdgcn_mfma_f32_16x16x32_bf16(aq[ks], bb[nt], sa[nt], 0, 0, 0);
    }

    // ---- online softmax; pack P -> Ps (u = 4*lr + nt) ----
    #pragma unroll
    for (int r = 0; r < 4; ++r) {
      float sc = nrm[r];
      float s0 = sa[0][r] * sc, s1 = sa[1][r] * sc;
      float s2 = sa[2][r] * sc, s3 = sa[3][r] * sc;
      float tm = fmaxf(fmaxf(s0, s1), fmaxf(s2, s3));
      #pragma unroll
      for (int off = 8; off; off >>= 1) tm = fmaxf(tm, __shfl_xor(tm, off));
      float mn = fmaxf(m_run[r], tm);
      float al = __expf(m_run[r] - mn);
      m_run[r] = mn;
      float e0 = __expf(s0 - mn), e1 = __expf(s1 - mn);
      float e2 = __expf(s2 - mn), e3 = __expf(s3 - mn);
      float ps = (e0 + e1) + (e2 + e3);
      #pragma unroll
      for (int off = 8; off; off >>= 1) ps += __shfl_xor(ps, off);
      l_run[r] = l_run[r] * al + ps;
      int q = 16 * w + lg * 4 + r;
      uint2 pw; pw.x = pkbf(e0, e1); pw.y = pkbf(e2, e3);
      *(uint2*)(PsB + q * 128 + ((lr * 8) ^ ((q & 7) << 4))) = pw;
      if (lr == 0) alpha_s[q] = al;
    }
    __syncthreads();   // all waves done with Ks reads; Ps visible

    // write staged tile k+1 into Ks (safe: reads done; next reads after barrier 2)
    if (k + 1 < KT) {
      #pragma unroll
      for (int i = 0; i < 8; ++i)
        *(uint4*)(KsB + (r0 + 8 * i) * 512 + (cb ^ swzk)) = st[i];
    }

    // ---- PV: rescale acc, then acc += Kmt' * P ----
    #pragma unroll
    for (int nt = 0; nt < 4; ++nt) {
      float al = alpha_s[nt * 16 + lr];
      #pragma unroll
      for (int mt = 0; mt < 4; ++mt) acc[mt][nt] *= al;
    }
    #pragma unroll
    for (int ks = 0; ks < 2; ++ks) {
      bf16x8 pfr[4];
      #pragma unroll
      for (int nt = 0; nt < 4; ++nt)
        pfr[nt] = *(const bf16x8*)(PsB + (nt * 16 + lr) * 128 +
                                   ((ks * 64 + lg * 16) ^ ((lr & 7) << 4)));
      #pragma unroll
      for (int mt = 0; mt < 4; ++mt)
        #pragma unroll
        for (int nt = 0; nt < 4; ++nt)
          acc[mt][nt] = __builtin_amdgcn_mfma_f32_16x16x32_bf16(km[ks][mt], pfr[nt], acc[mt][nt], 0, 0, 0);
    }
    __syncthreads();   // Ks[k+1] visible; Ps reads done before next overwrite
  }

  // ---- epilogue: store O~ as [q][c] (8B packed) and (m,l) ----
  __bf16* op = Opart + ((size_t)(js * BS + b) * NQT + qt) * QB * CH;
  #pragma unroll
  for (int mt = 0; mt < 4; ++mt) {
    const int cbn = 64 * w + mt * 16 + lg * 4;
    #pragma unroll
    for (int nt = 0; nt < 4; ++nt) {
      const int q = nt * 16 + lr;
      uint2 pw;
      pw.x = pkbf(acc[mt][nt][0], acc[mt][nt][1]);
      pw.y = pkbf(acc[mt][nt][2], acc[mt][nt][3]);
      *(uint2*)(op + (size_t)q * CH + cbn) = pw;
    }
  }
  if (lr == 0) {
    #pragma unroll
    for (int r = 0; r < 4; ++r) {
      int qg = q0 + 16 * w + lg * 4 + r;
      ml[(size_t)(js * BS + b) * HW + qg] = make_float2(m_run[r], l_run[r]);
    }
  }
}

// ---------------- combine partials + blend ----------------
__global__ __launch_bounds__(256) void combine_kernel(
    const __bf16* __restrict__ Opart, const float2* __restrict__ ml,
    const float* __restrict__ F, const float* __restrict__ mask,
    const float* __restrict__ flags, float* __restrict__ out, int jn)
{
  const int bid = blockIdx.x;
  const int cq = bid & 3, chunk = bid >> 2;
  const int t = threadIdx.x;
  const int qg = chunk * 256 + t;
  const int b  = qg >> 12, q = qg & 4095;
  const int qt = q >> 6, ql = q & 63;

  float mv[4], lv[4];
  float m = -1e30f;
  for (int js = 0; js < jn; ++js) {
    float2 e = ml[(size_t)(js * BS + b) * HW + q];
    mv[js] = e.x; lv[js] = e.y;
    m = fmaxf(m, e.x);
  }
  float L = 0.f, sc[4];
  for (int js = 0; js < jn; ++js) {
    sc[js] = __expf(mv[js] - m);
    L += lv[js] * sc[js];
  }
  float inv = 1.f / L;
  float msk = mask[b * HW + q];
  float w1 = 1.f - msk;
  bool skip = flags[b] > 0.5f;

  const __bf16* opq[4];
  for (int js = 0; js < jn; ++js)
    opq[js] = Opart + (((size_t)(js * BS + b) * NQT + qt) * QB + ql) * CH;

  for (int c0 = cq * 64; c0 < cq * 64 + 64; c0 += 8) {
    float s8[8];
    #pragma unroll
    for (int e = 0; e < 8; ++e) s8[e] = 0.f;
    for (int js = 0; js < jn; ++js) {
      bf16x8 v = *(const bf16x8*)(opq[js] + c0);
      #pragma unroll
      for (int e = 0; e < 8; ++e) s8[e] += (float)v[e] * sc[js];
    }
    #pragma unroll
    for (int e = 0; e < 8; ++e) {
      size_t idx = ((size_t)b * CH + c0 + e) * HW + q;
      float f = F[idx];
      out[idx] = skip ? f : (s8[e] * inv * w1 + f * msk);
    }
  }
}

extern "C" void kernel_launch(void* const* d_in, const int* in_sizes, int n_in,
                              void* d_out, int out_size, void* d_ws, size_t ws_size,
                              hipStream_t stream) {
  const float* F    = (const float*)d_in[0];
  const float* mask = (const float*)d_in[1];
  float* out = (float*)d_out;

  char* p = (char*)d_ws;
  __bf16* Kn  = (__bf16*)p;  p += (size_t)BS * HW * CH * 2;
  __bf16* Kmt = (__bf16*)p;  p += (size_t)BS * HW * CH * 2;
  float* norms = (float*)p;  p += (size_t)BS * HW * 4;
  float* flags = (float*)p;  p += 256;
  size_t used = (size_t)(p - (char*)d_ws);

  int jn = 2;
  while (jn > 1) {
    size_t need = used + (size_t)jn * ((size_t)BS * HW * 8 + (size_t)BS * NQT * QB * CH * 2);
    if (need <= ws_size) break;
    jn >>= 1;
  }
  float2* ml = (float2*)p;   p += (size_t)jn * BS * HW * 8;
  __bf16* Opart = (__bf16*)p;

  prep_kernel<<<dim3(HW / 32, BS), 256, 0, stream>>>(F, mask, Kn, Kmt, norms);
  skip_kernel<<<BS, 256, 0, stream>>>(mask, flags);
  attn_kernel<<<dim3(NQT * 4 * jn), 256, 0, stream>>>(Kn, Kmt, norms, Opart, ml, jn);
  combine_kernel<<<dim3(256), 256, 0, stream>>>(Opart, ml, F, mask, flags, out, jn);
}